// Round 4
// baseline (655.354 us; speedup 1.0000x reference)
//
#include <hip/hip_runtime.h>
#include <hip/hip_bf16.h>

// Problem constants (fixed shapes from setup_inputs)
#define M_DIM 8192   // B*S = 4*2048
#define N_DIM 4096   // D_OUT
#define DK    4096   // D_IN
#define R_DIM 64
#define KX    4160   // DK + R_DIM (K-extended GEMM)
#define SPLITK 8
#define KCHUNK (DK / SPLITK)  // 512
// SCALE = ALPHA/K = 16/16 = 1.0

// main gemm tiling: 256x256 tile, BK=32, 8 waves (2Mx4N)
// A staged through a 4-deep LDS ring; B read DIRECT from global (L2/L3) into
// registers, 1 tile ahead -- halves LDS port traffic (the binding resource).
#define BM 256
#define BN 256
#define BK 32
#define NT (KX / BK)            // 130 K-tiles
#define ATILE (BM * BK)         // 8192 shorts = 16 KB per A buffer
#define RING 4                  // 4 * 16 KB = 64 KB LDS

typedef __bf16 bf16x8 __attribute__((ext_vector_type(8)));
typedef float f32x4 __attribute__((ext_vector_type(4)));
typedef unsigned short ushort8 __attribute__((ext_vector_type(8)));

__device__ __forceinline__ unsigned short f2bf_rne(float f) {
  union { float f; unsigned int u; } v; v.f = f;
  unsigned int u = v.u;
  return (unsigned short)((u + 0x7fffu + ((u >> 16) & 1u)) >> 16);
}

// async global->LDS, 16B per lane; lds dest is wave-uniform base + lane*16
__device__ __forceinline__ void load16_to_lds(const void* g, void* l) {
  __builtin_amdgcn_global_load_lds(
      (__attribute__((address_space(1))) void*)(unsigned long long)(const char*)g,
      (__attribute__((address_space(3))) void*)(unsigned int)(unsigned long long)(char*)l,
      16, 0, 0);
}

// ---------------- fp32 -> bf16 conversion, all four tensors in ONE launch ----------------
// job ranges are exact multiples of 2048 elems (= 1 block) -> block-uniform branch
__global__ __launch_bounds__(256) void cvt_all_kernel(
    const float* __restrict__ x, const float* __restrict__ W,
    const float* __restrict__ B, const float* __restrict__ A,
    unsigned short* __restrict__ xext, unsigned short* __restrict__ wext,
    unsigned short* __restrict__ abf) {
  const int b = blockIdx.x;
  const float* src; unsigned short* dst;
  int shift, mask, rowstride, coloff; long long base;
  if (b < 16384)      { src = x; dst = xext; shift = 12; mask = 4095; rowstride = KX; coloff = 0;  base = (long long)b * 2048; }
  else if (b < 24576) { src = W; dst = wext; shift = 12; mask = 4095; rowstride = KX; coloff = 0;  base = (long long)(b - 16384) * 2048; }
  else if (b < 24704) { src = B; dst = wext; shift = 6;  mask = 63;   rowstride = KX; coloff = DK; base = (long long)(b - 24576) * 2048; }
  else                { src = A; dst = abf;  shift = 12; mask = 4095; rowstride = DK; coloff = 0;  base = (long long)(b - 24704) * 2048; }
  long long idx = base + (long long)threadIdx.x * 8;
  long long row = idx >> shift;
  int col = (int)(idx & mask);
  float4 f0 = *(const float4*)(src + idx);
  float4 f1 = *(const float4*)(src + idx + 4);
  ushort8 o;
  o[0] = f2bf_rne(f0.x); o[1] = f2bf_rne(f0.y);
  o[2] = f2bf_rne(f0.z); o[3] = f2bf_rne(f0.w);
  o[4] = f2bf_rne(f1.x); o[5] = f2bf_rne(f1.y);
  o[6] = f2bf_rne(f1.z); o[7] = f2bf_rne(f1.w);
  *(ushort8*)(dst + row * (long long)rowstride + coloff + col) = o;
}

// ---------------- z partials: zpart[kc] = xext[:, kc*512:(kc+1)*512] @ Abf^T ----------------
__global__ __launch_bounds__(256) void zgemm_kernel(
    const unsigned short* __restrict__ Xg,   // [M_DIM][KX] bf16
    const unsigned short* __restrict__ Ab,   // [R_DIM][DK] bf16
    float* __restrict__ zpart) {             // [SPLITK][M_DIM][64] fp32
  __shared__ unsigned short As[128][32];  // 8 KB (x rows)
  __shared__ unsigned short Bs[64][32];   // 4 KB (A rows)

  const int tid = threadIdx.x;
  const int wave = tid >> 6;
  const int lane = tid & 63;
  const int rowBase = blockIdx.x * 128;
  const int kc = blockIdx.y;
  const int kBase = kc * KCHUNK;
  const int wm = wave * 32;

  const int c0 = wave, c1 = wave + 4;
  const int srow = lane >> 2;
  const int sseg = (lane & 3) * 8;

  const unsigned short* aP0 = Xg + (size_t)(rowBase + c0 * 16 + srow) * KX + kBase + sseg;
  const unsigned short* aP1 = Xg + (size_t)(rowBase + c1 * 16 + srow) * KX + kBase + sseg;
  const unsigned short* bP0 = Ab + (size_t)(wave * 16 + srow) * DK + kBase + sseg;
  unsigned short* aL0 = &As[c0 * 16][0];
  unsigned short* aL1 = &As[c1 * 16][0];
  unsigned short* bL0 = &Bs[wave * 16][0];

  f32x4 acc[2][4] = {};
  const int fr = lane & 15;
  const int fk = (lane >> 4) * 8;

  for (int k0 = 0; k0 < KCHUNK; k0 += 32) {
    __syncthreads();
    load16_to_lds(aP0 + k0, aL0);
    load16_to_lds(aP1 + k0, aL1);
    load16_to_lds(bP0 + k0, bL0);
    __syncthreads();

    bf16x8 afrag[2], bfrag[4];
#pragma unroll
    for (int i = 0; i < 2; ++i)
      afrag[i] = *(const bf16x8*)&As[wm + i * 16 + fr][fk];
#pragma unroll
    for (int j = 0; j < 4; ++j)
      bfrag[j] = *(const bf16x8*)&Bs[j * 16 + fr][fk];
#pragma unroll
    for (int i = 0; i < 2; ++i)
#pragma unroll
      for (int j = 0; j < 4; ++j)
        acc[i][j] = __builtin_amdgcn_mfma_f32_16x16x32_bf16(afrag[i], bfrag[j],
                                                            acc[i][j], 0, 0, 0);
  }

  const int quad = lane >> 4;
#pragma unroll
  for (int j = 0; j < 4; ++j) {
    int col = j * 16 + fr;
#pragma unroll
    for (int i = 0; i < 2; ++i) {
      int row0 = rowBase + wm + i * 16 + quad * 4;
#pragma unroll
      for (int r = 0; r < 4; ++r)
        zpart[((size_t)kc * M_DIM + row0 + r) * R_DIM + col] = acc[i][j][r];
    }
  }
}

// ---------------- reduce partials, soft top-k mask, write bf16 into x_ext tail ----------------
__global__ __launch_bounds__(256) void mask_kernel(
    const float* __restrict__ zpart, unsigned short* __restrict__ xext) {
  const int wave = threadIdx.x >> 6;
  const int lane = threadIdx.x & 63;
  const int row = blockIdx.x * 4 + wave;

  float v = 0.f;
#pragma unroll
  for (int k = 0; k < SPLITK; ++k)
    v += zpart[((size_t)k * M_DIM + row) * R_DIM + lane];

  float a = fabsf(v);
  // rank-select the 16th-largest |z| (tie-safe): cnt_gt <= 15 < cnt_ge
  int cnt_gt = 0, cnt_ge = 0;
#pragma unroll
  for (int i = 0; i < 64; ++i) {
    float o = __shfl(a, i);
    cnt_gt += (o > a) ? 1 : 0;
    cnt_ge += (o >= a) ? 1 : 0;
  }
  float cand = (cnt_gt <= 15 && cnt_ge > 15) ? a : -1.f;
#pragma unroll
  for (int off = 32; off; off >>= 1) cand = fmaxf(cand, __shfl_xor(cand, off));
  float thr = cand;
  float mask = 1.f / (1.f + __expf(-(a - thr) * 10.0f));  // TEMP=0.1
  xext[(size_t)row * KX + DK + lane] = f2bf_rne(v * mask);  // SCALE == 1.0
}

// ---------------- main GEMM: out[m][n] = sum_k xext[m][k]*wext[n][k] + bias[n] ----------------
// A: 4-deep LDS ring (stage t+4 after barrier t; reads prefetch 1 tile ahead
// into registers). B: direct global->register loads, 1 tile ahead (each frag =
// 16 fully-consumed 64B lines of wext, L2/L3-resident panel). Counted waits:
// steady vmcnt(6) = allow {stage t+3 (2 loads) + B(t+1) (4 loads)}, forcing
// stage(t+2) landed for next iter's LDS reads; lgkmcnt(8) = own A-reads of
// slot t done (frees slot t for overwrite after the barrier).
__global__ __launch_bounds__(512, 2) void gemm_kernel(
    const unsigned short* __restrict__ Ag,   // [M_DIM][KX] bf16
    const unsigned short* __restrict__ Bg,   // [N_DIM][KX] bf16
    const float* __restrict__ bias,
    float* __restrict__ out) {
  extern __shared__ unsigned short sm[];  // RING * ATILE shorts = 64 KB

  const int tid = threadIdx.x;
  const int w = tid >> 6;
  const int lane = tid & 63;

  // T1: 512 blocks, 8 XCDs; each XCD owns an 8bm x 8bn sub-grid (balances the
  // per-XCD A and B working sets at ~17 MB each).
  const int bid = blockIdx.x;
  const int xcd = bid & 7;
  const int id = bid >> 3;                 // 0..63
  const int bm = (xcd & 3) * 8 + (id >> 3);
  const int bn = (xcd >> 2) * 8 + (id & 7);
  const int rowBase = bm * BM;
  const int colBase = bn * BN;

  // wave tile: 2 (M) x 4 (N); per-wave output 128x64
  const int wm = (w >> 2) * 128;
  const int wn = (w & 3) * 64;

  // ---- A staging setup -----------------------------------------------------
  // LDS dest linear (wave-uniform base + lane*16B); read-side swizzle
  // slot' = slot ^ ((row>>1)&3) realized by pre-swizzling the GLOBAL source.
  const int srow = lane >> 2;                                // 0..15
  const int sseg = (((lane & 3) ^ ((lane >> 3) & 3)) * 8);   // swizzled 8-short seg
  const int c0 = w * 2, c1 = w * 2 + 1;                      // 16-row chunks
  const unsigned short* aS0 = Ag + (size_t)(rowBase + c0 * 16 + srow) * KX + sseg;
  const unsigned short* aS1 = Ag + (size_t)(rowBase + c1 * 16 + srow) * KX + sseg;
  const int aD0 = c0 * 512, aD1 = c1 * 512;                  // shorts, wave-uniform

#define STAGE_A(slot, koff)                                      \
  do {                                                           \
    load16_to_lds(aS0 + (koff), &sm[(slot) * ATILE + aD0]);      \
    load16_to_lds(aS1 + (koff), &sm[(slot) * ATILE + aD1]);      \
  } while (0)

  f32x4 acc[8][4] = {};
  const int fr = lane & 15;
  const int q = lane >> 4;
  const int rdc = ((q ^ ((fr >> 1) & 3)) * 8);  // T2 read-side XOR (2-way = free)

  // ---- B direct-global fragment pointers (per j, advanced by koff) ---------
  const int fkb = q * 8;  // k-offset within frag, shorts
  const unsigned short* bQ0 = Bg + (size_t)(colBase + wn + 0 * 16 + fr) * KX + fkb;
  const unsigned short* bQ1 = Bg + (size_t)(colBase + wn + 1 * 16 + fr) * KX + fkb;
  const unsigned short* bQ2 = Bg + (size_t)(colBase + wn + 2 * 16 + fr) * KX + fkb;
  const unsigned short* bQ3 = Bg + (size_t)(colBase + wn + 3 * 16 + fr) * KX + fkb;

#define BLOAD(BF, koff)                                 \
  do {                                                  \
    BF[0] = *(const bf16x8*)(bQ0 + (koff));             \
    BF[1] = *(const bf16x8*)(bQ1 + (koff));             \
    BF[2] = *(const bf16x8*)(bQ2 + (koff));             \
    BF[3] = *(const bf16x8*)(bQ3 + (koff));             \
  } while (0)

#define RD_A(AF, slot)                                                        \
  do {                                                                        \
    _Pragma("unroll")                                                         \
    for (int i_ = 0; i_ < 8; ++i_)                                            \
      AF[i_] = *(const bf16x8*)&sm[(slot) * ATILE + (wm + i_ * 16 + fr) * 32 + rdc]; \
  } while (0)

#define MFMA_ALL(AF, BF)                                                      \
  do {                                                                        \
    __builtin_amdgcn_s_setprio(1);                                            \
    _Pragma("unroll")                                                         \
    for (int i_ = 0; i_ < 8; ++i_)                                            \
      _Pragma("unroll")                                                       \
      for (int j_ = 0; j_ < 4; ++j_)                                          \
        acc[i_][j_] = __builtin_amdgcn_mfma_f32_16x16x32_bf16(                \
            AF[i_], BF[j_], acc[i_][j_], 0, 0, 0);                            \
    __builtin_amdgcn_s_setprio(0);                                            \
  } while (0)

#define WAIT_BARRIER(VM)                                                      \
  do {                                                                        \
    asm volatile("s_waitcnt vmcnt(" #VM ") lgkmcnt(8)" ::: "memory");         \
    __builtin_amdgcn_sched_barrier(0);                                        \
    __builtin_amdgcn_s_barrier();                                             \
    __builtin_amdgcn_sched_barrier(0);                                        \
  } while (0)

  // ---- prologue: fill the A ring (tiles 0..3) + B(0); slots 0,1 resident ---
  STAGE_A(0, 0);
  STAGE_A(1, 32);
  STAGE_A(2, 64);
  STAGE_A(3, 96);
  bf16x8 afA[8], bfA[4], afB[8], bfB[4];
  BLOAD(bfA, 0);
  // allow {stage2(2) + stage3(2) + B0(4)} = 8 -> stages 0,1 landed
  asm volatile("s_waitcnt vmcnt(8)" ::: "memory");
  __builtin_amdgcn_sched_barrier(0);
  __builtin_amdgcn_s_barrier();
  __builtin_amdgcn_sched_barrier(0);
  RD_A(afA, 0);  // A fragments of tile 0

  // ---- main loop: pairs (t, t+1), t=0..125; stages tiles 4..129 ------------
  for (int tp = 0; tp < 126; tp += 2) {
    // t = tp (even): prefetch B(t+1)+A(t+1), compute tile t on (afA,bfA)
    BLOAD(bfB, (tp + 1) * 32);
    RD_A(afB, (tp + 1) & 3);
    MFMA_ALL(afA, bfA);
    WAIT_BARRIER(6);
    STAGE_A(tp & 3, (tp + 4) * 32);
    // t = tp+1 (odd): prefetch B(t+1)+A(t+1), compute on (afB,bfB)
    BLOAD(bfA, (tp + 2) * 32);
    RD_A(afA, (tp + 2) & 3);
    MFMA_ALL(afB, bfB);
    WAIT_BARRIER(6);
    STAGE_A((tp + 1) & 3, (tp + 5) * 32);
  }

  // ---- tail: tiles 126..129 (no staging beyond 129) ------------------------
  // t=126 (even, afA/bfA hold tile 126)
  BLOAD(bfB, 127 * 32);
  RD_A(afB, 127 & 3);
  MFMA_ALL(afA, bfA);
  WAIT_BARRIER(6);   // force stage(128); {stage129(2)+B127(4)} stay in flight
  // t=127
  BLOAD(bfA, 128 * 32);
  RD_A(afA, 128 & 3);
  MFMA_ALL(afB, bfB);
  WAIT_BARRIER(4);   // force stage(129); {B128(4)} stays in flight
  // t=128
  BLOAD(bfB, 129 * 32);
  RD_A(afB, 129 & 3);
  MFMA_ALL(afA, bfA);
  // t=129 (compiler inserts the final lgkm/vm waits for afB/bfB)
  MFMA_ALL(afB, bfB);

#undef STAGE_A
#undef BLOAD
#undef RD_A
#undef MFMA_ALL
#undef WAIT_BARRIER

  // ---- epilogue: C/D layout col=lane&15, row=(lane>>4)*4+reg ---------------
#pragma unroll
  for (int j = 0; j < 4; ++j) {
    const int col = colBase + wn + j * 16 + fr;
    const float bv = bias[col];
#pragma unroll
    for (int i = 0; i < 8; ++i) {
      const int r0 = rowBase + wm + i * 16 + q * 4;
#pragma unroll
      for (int r = 0; r < 4; ++r)
        out[(size_t)(r0 + r) * N_DIM + col] = acc[i][j][r] + bv;
    }
  }
}

extern "C" void kernel_launch(void* const* d_in, const int* in_sizes, int n_in,
                              void* d_out, int out_size, void* d_ws, size_t ws_size,
                              hipStream_t stream) {
  const float* x    = (const float*)d_in[0];  // (4,2048,4096)
  const float* A    = (const float*)d_in[1];  // (64,4096)
  const float* B    = (const float*)d_in[2];  // (4096,64)
  const float* W    = (const float*)d_in[3];  // (4096,4096)
  const float* bias = (const float*)d_in[4];  // (4096,)
  float* out = (float*)d_out;

  // workspace layout (all 16B-aligned):
  //   xext  [8192][4160] bf16  = 68.16 MB
  //   wext  [4096][4160] bf16  = 34.08 MB
  //   abf   [64][4096]   bf16  =  0.52 MB
  //   zpart [8][8192][64] fp32 = 16.78 MB
  unsigned short* xext = (unsigned short*)d_ws;
  unsigned short* wext = xext + (size_t)M_DIM * KX;
  unsigned short* abf  = wext + (size_t)N_DIM * KX;
  float*          zpart = (float*)(abf + (size_t)R_DIM * DK);

  // all four fp32->bf16 conversions in one launch
  cvt_all_kernel<<<24832, 256, 0, stream>>>(x, W, B, A, xext, wext, abf);

  // z partials via MFMA split-K GEMM
  dim3 zgrid(M_DIM / 128, SPLITK);  // 64 x 8
  zgemm_kernel<<<zgrid, 256, 0, stream>>>(xext, abf, zpart);
  // reduce + soft-topk mask -> x_ext[:, 4096:]
  mask_kernel<<<M_DIM / 4, 256, 0, stream>>>(zpart, xext);

  // main GEMM: 512 blocks (32 bm x 16 bn), 512 threads, 64 KB dynamic LDS
  gemm_kernel<<<dim3(32 * 16), 512, RING * ATILE * sizeof(unsigned short), stream>>>(
      xext, wext, bias, out);
}

// Round 5
// 539.301 us; speedup vs baseline: 1.2152x; 1.2152x over previous
//
#include <hip/hip_runtime.h>
#include <hip/hip_bf16.h>

// Problem constants (fixed shapes from setup_inputs)
#define M_DIM 8192   // B*S = 4*2048
#define N_DIM 4096   // D_OUT
#define DK    4096   // D_IN
#define R_DIM 64
#define KX    4160   // DK + R_DIM (K-extended GEMM)
#define SPLITK 8
#define KCHUNK (DK / SPLITK)  // 512
// SCALE = ALPHA/K = 16/16 = 1.0

// main gemm tiling: 256x256 tile, BK=32, 4-deep LDS ring, 8 waves (2Mx4N)
#define BM 256
#define BN 256
#define BK 32
#define NT (KX / BK)            // 130 K-tiles
#define ATILE (BM * BK)         // 8192 shorts = 16 KB per operand per buffer
#define BUFS (2 * ATILE)        // 16384 shorts per ring slot (A + B)
#define RING 4                  // 4 * 32 KB = 128 KB LDS

typedef __bf16 bf16x8 __attribute__((ext_vector_type(8)));
typedef float f32x4 __attribute__((ext_vector_type(4)));
typedef unsigned short ushort8 __attribute__((ext_vector_type(8)));

__device__ __forceinline__ unsigned short f2bf_rne(float f) {
  union { float f; unsigned int u; } v; v.f = f;
  unsigned int u = v.u;
  return (unsigned short)((u + 0x7fffu + ((u >> 16) & 1u)) >> 16);
}

// async global->LDS, 16B per lane; lds dest is wave-uniform base + lane*16
__device__ __forceinline__ void load16_to_lds(const void* g, void* l) {
  __builtin_amdgcn_global_load_lds(
      (__attribute__((address_space(1))) void*)(unsigned long long)(const char*)g,
      (__attribute__((address_space(3))) void*)(unsigned int)(unsigned long long)(char*)l,
      16, 0, 0);
}

// ---------------- fp32 -> bf16 conversion for W, B, A (x handled in zgemm) ----------------
// job ranges are exact multiples of 2048 elems (= 1 block) -> block-uniform branch
__global__ __launch_bounds__(256) void cvt_wba_kernel(
    const float* __restrict__ W, const float* __restrict__ B,
    const float* __restrict__ A,
    unsigned short* __restrict__ wext, unsigned short* __restrict__ abf) {
  const int b = blockIdx.x;
  const float* src; unsigned short* dst;
  int shift, mask, rowstride, coloff; long long base;
  if (b < 8192)      { src = W; dst = wext; shift = 12; mask = 4095; rowstride = KX; coloff = 0;  base = (long long)b * 2048; }
  else if (b < 8320) { src = B; dst = wext; shift = 6;  mask = 63;   rowstride = KX; coloff = DK; base = (long long)(b - 8192) * 2048; }
  else               { src = A; dst = abf;  shift = 12; mask = 4095; rowstride = DK; coloff = 0;  base = (long long)(b - 8320) * 2048; }
  long long idx = base + (long long)threadIdx.x * 8;
  long long row = idx >> shift;
  int col = (int)(idx & mask);
  float4 f0 = *(const float4*)(src + idx);
  float4 f1 = *(const float4*)(src + idx + 4);
  ushort8 o;
  o[0] = f2bf_rne(f0.x); o[1] = f2bf_rne(f0.y);
  o[2] = f2bf_rne(f0.z); o[3] = f2bf_rne(f0.w);
  o[4] = f2bf_rne(f1.x); o[5] = f2bf_rne(f1.y);
  o[6] = f2bf_rne(f1.z); o[7] = f2bf_rne(f1.w);
  *(ushort8*)(dst + row * (long long)rowstride + coloff + col) = o;
}

// ---------------- fused x-cvt + z partials ----------------
// Block (rowblk, kc): reads x fp32 [128 rows][512 k-chunk], converts to bf16
// (staged in LDS for MFMA AND stored to xext -- each (row,k) covered exactly
// once across the grid), computes zpart[kc] = x_chunk @ Abf_chunk^T.
__global__ __launch_bounds__(256) void zgemm_kernel(
    const float* __restrict__ Xf,            // [M_DIM][DK] fp32
    const unsigned short* __restrict__ Ab,   // [R_DIM][DK] bf16
    unsigned short* __restrict__ xext,       // [M_DIM][KX] bf16 (writes [:, :DK])
    float* __restrict__ zpart) {             // [SPLITK][M_DIM][64] fp32
  __shared__ unsigned short As[128][32];  // 8 KB (x rows, bf16)
  __shared__ unsigned short Bs[64][32];   // 4 KB (A rows)

  const int tid = threadIdx.x;
  const int wave = tid >> 6;
  const int lane = tid & 63;
  const int rowBase = blockIdx.x * 128;
  const int kc = blockIdx.y;
  const int kBase = kc * KCHUNK;
  const int wm = wave * 32;

  // Ab staging (global_load_lds): wave w stages rows w*16..w*16+15
  const int srowL = lane >> 2;
  const int ssegL = (lane & 3) * 8;
  const unsigned short* bP0 = Ab + (size_t)(wave * 16 + srowL) * DK + kBase + ssegL;
  unsigned short* bL0 = &Bs[wave * 16][0];

  // x staging (reg-convert): thread covers rows (tid>>2) and (tid>>2)+64,
  // k-segment (tid&3)*8 -- 4 threads cover a row's 32-k stripe (128B read)
  const int xrow = tid >> 2;
  const int xseg = (tid & 3) * 8;

  f32x4 acc[2][4] = {};
  const int fr = lane & 15;
  const int fk = (lane >> 4) * 8;

  for (int k0 = 0; k0 < KCHUNK; k0 += 32) {
    __syncthreads();
    load16_to_lds(bP0 + k0, bL0);
#pragma unroll
    for (int p = 0; p < 2; ++p) {
      const int row = xrow + p * 64;
      const size_t gk = (size_t)(rowBase + row) * DK + kBase + k0 + xseg;
      float4 f0 = *(const float4*)(Xf + gk);
      float4 f1 = *(const float4*)(Xf + gk + 4);
      ushort8 o;
      o[0] = f2bf_rne(f0.x); o[1] = f2bf_rne(f0.y);
      o[2] = f2bf_rne(f0.z); o[3] = f2bf_rne(f0.w);
      o[4] = f2bf_rne(f1.x); o[5] = f2bf_rne(f1.y);
      o[6] = f2bf_rne(f1.z); o[7] = f2bf_rne(f1.w);
      *(ushort8*)&As[row][xseg] = o;
      *(ushort8*)(xext + (size_t)(rowBase + row) * KX + kBase + k0 + xseg) = o;
    }
    __syncthreads();

    bf16x8 afrag[2], bfrag[4];
#pragma unroll
    for (int i = 0; i < 2; ++i)
      afrag[i] = *(const bf16x8*)&As[wm + i * 16 + fr][fk];
#pragma unroll
    for (int j = 0; j < 4; ++j)
      bfrag[j] = *(const bf16x8*)&Bs[j * 16 + fr][fk];
#pragma unroll
    for (int i = 0; i < 2; ++i)
#pragma unroll
      for (int j = 0; j < 4; ++j)
        acc[i][j] = __builtin_amdgcn_mfma_f32_16x16x32_bf16(afrag[i], bfrag[j],
                                                            acc[i][j], 0, 0, 0);
  }

  const int quad = lane >> 4;
#pragma unroll
  for (int j = 0; j < 4; ++j) {
    int col = j * 16 + fr;
#pragma unroll
    for (int i = 0; i < 2; ++i) {
      int row0 = rowBase + wm + i * 16 + quad * 4;
#pragma unroll
      for (int r = 0; r < 4; ++r)
        zpart[((size_t)kc * M_DIM + row0 + r) * R_DIM + col] = acc[i][j][r];
    }
  }
}

// ---------------- reduce partials, soft top-k mask, write bf16 into x_ext tail ----------------
__global__ __launch_bounds__(256) void mask_kernel(
    const float* __restrict__ zpart, unsigned short* __restrict__ xext) {
  const int wave = threadIdx.x >> 6;
  const int lane = threadIdx.x & 63;
  const int row = blockIdx.x * 4 + wave;

  float v = 0.f;
#pragma unroll
  for (int k = 0; k < SPLITK; ++k)
    v += zpart[((size_t)k * M_DIM + row) * R_DIM + lane];

  float a = fabsf(v);
  // rank-select the 16th-largest |z| (tie-safe): cnt_gt <= 15 < cnt_ge
  int cnt_gt = 0, cnt_ge = 0;
#pragma unroll
  for (int i = 0; i < 64; ++i) {
    float o = __shfl(a, i);
    cnt_gt += (o > a) ? 1 : 0;
    cnt_ge += (o >= a) ? 1 : 0;
  }
  float cand = (cnt_gt <= 15 && cnt_ge > 15) ? a : -1.f;
#pragma unroll
  for (int off = 32; off; off >>= 1) cand = fmaxf(cand, __shfl_xor(cand, off));
  float thr = cand;
  float mask = 1.f / (1.f + __expf(-(a - thr) * 10.0f));  // TEMP=0.1
  xext[(size_t)row * KX + DK + lane] = f2bf_rne(v * mask);  // SCALE == 1.0
}

// ---------------- main GEMM: out[m][n] = sum_k xext[m][k]*wext[n][k] + bias[n] ----------------
// (Round-3 proven version, verbatim: 244.7 us, MfmaUtil 53%, 0 bank conflicts.)
// 256x256 tile, BK=32, 8 waves (2Mx4N), 4-deep LDS ring, REGISTER-double-buffered
// fragments: tile t+1's ds_reads issue BEFORE tile t's MFMAs; post-MFMA wait is
// counted vmcnt(4)+lgkmcnt(12); one barrier per tile.
__global__ __launch_bounds__(512, 2) void gemm_kernel(
    const unsigned short* __restrict__ Ag,   // [M_DIM][KX] bf16
    const unsigned short* __restrict__ Bg,   // [N_DIM][KX] bf16
    const float* __restrict__ bias,
    float* __restrict__ out) {
  extern __shared__ unsigned short sm[];  // RING * BUFS shorts = 128 KB

  const int tid = threadIdx.x;
  const int w = tid >> 6;
  const int lane = tid & 63;

  // T1: 512 blocks = 8 XCDs x 64; each XCD gets 4 consecutive bm rows
  const int bid = blockIdx.x;
  const int swz = (bid & 7) * 64 + (bid >> 3);
  const int bm = swz >> 4;   // 0..31
  const int bn = swz & 15;   // 0..15
  const int rowBase = bm * BM;
  const int colBase = bn * BN;

  // wave tile: 2 (M) x 4 (N); per-wave output 128x64
  const int wm = (w >> 2) * 128;
  const int wn = (w & 3) * 64;

  // ---- staging setup -------------------------------------------------------
  // LDS dest linear (wave-uniform base + lane*16B); read-side swizzle
  // slot' = slot ^ ((row>>1)&3) realized by pre-swizzling the GLOBAL source.
  const int srow = lane >> 2;                                // 0..15
  const int sseg = (((lane & 3) ^ ((lane >> 3) & 3)) * 8);   // swizzled 8-short seg
  const int c0 = w * 2, c1 = w * 2 + 1;                      // 16-row chunks
  const unsigned short* aS0 = Ag + (size_t)(rowBase + c0 * 16 + srow) * KX + sseg;
  const unsigned short* aS1 = Ag + (size_t)(rowBase + c1 * 16 + srow) * KX + sseg;
  const unsigned short* bS0 = Bg + (size_t)(colBase + c0 * 16 + srow) * KX + sseg;
  const unsigned short* bS1 = Bg + (size_t)(colBase + c1 * 16 + srow) * KX + sseg;
  const int aD0 = c0 * 512, aD1 = c1 * 512;                  // shorts, wave-uniform
  const int bD0 = ATILE + c0 * 512, bD1 = ATILE + c1 * 512;

#define STAGE(bufS, koff)                                \
  do {                                                   \
    load16_to_lds(aS0 + (koff), &sm[(bufS) + aD0]);      \
    load16_to_lds(aS1 + (koff), &sm[(bufS) + aD1]);      \
    load16_to_lds(bS0 + (koff), &sm[(bufS) + bD0]);      \
    load16_to_lds(bS1 + (koff), &sm[(bufS) + bD1]);      \
  } while (0)

  f32x4 acc[8][4] = {};
  const int fr = lane & 15;
  const int q = lane >> 4;
  const int rdc = ((q ^ ((fr >> 1) & 3)) * 8);  // T2 read-side XOR (2-way = free)

#define RD_FRAGS(AF, BF, S)                                                   \
  do {                                                                        \
    _Pragma("unroll")                                                         \
    for (int i_ = 0; i_ < 8; ++i_)                                            \
      AF[i_] = *(const bf16x8*)&sm[(S) + (wm + i_ * 16 + fr) * 32 + rdc];     \
    _Pragma("unroll")                                                         \
    for (int j_ = 0; j_ < 4; ++j_)                                            \
      BF[j_] = *(const bf16x8*)&sm[(S) + ATILE + (wn + j_ * 16 + fr) * 32 + rdc]; \
  } while (0)

#define MFMA_ALL(AF, BF)                                                      \
  do {                                                                        \
    __builtin_amdgcn_s_setprio(1);                                            \
    _Pragma("unroll")                                                         \
    for (int i_ = 0; i_ < 8; ++i_)                                            \
      _Pragma("unroll")                                                       \
      for (int j_ = 0; j_ < 4; ++j_)                                          \
        acc[i_][j_] = __builtin_amdgcn_mfma_f32_16x16x32_bf16(                \
            AF[i_], BF[j_], acc[i_][j_], 0, 0, 0);                            \
    __builtin_amdgcn_s_setprio(0);                                            \
  } while (0)

#define WAIT_BARRIER(VM)                                                      \
  do {                                                                        \
    asm volatile("s_waitcnt vmcnt(" #VM ") lgkmcnt(12)" ::: "memory");        \
    __builtin_amdgcn_sched_barrier(0);                                        \
    __builtin_amdgcn_s_barrier();                                             \
    __builtin_amdgcn_sched_barrier(0);                                        \
  } while (0)

  // ---- prologue: fill the 4-deep ring (tiles 0..3), 16 loads in flight ----
  STAGE(0 * BUFS, 0);
  STAGE(1 * BUFS, 32);
  STAGE(2 * BUFS, 64);
  STAGE(3 * BUFS, 96);
  // slots 0 AND 1 must be resident block-wide before iter 0 (it reads slot 1)
  asm volatile("s_waitcnt vmcnt(8)" ::: "memory");
  __builtin_amdgcn_sched_barrier(0);
  __builtin_amdgcn_s_barrier();
  __builtin_amdgcn_sched_barrier(0);

  bf16x8 afA[8], bfA[4], afB[8], bfB[4];
  RD_FRAGS(afA, bfA, 0);  // fragments of tile 0

  // ---- main loop: pairs t=(tp, tp+1), tp = 0..124; stages tiles 4..129 -----
  int koff = 128;
  for (int tp = 0; tp < 126; tp += 2) {
    const int s0 = (tp & 3) * BUFS;
    const int s1 = ((tp + 1) & 3) * BUFS;
    const int s2 = ((tp + 2) & 3) * BUFS;
    // t = tp: prefetch fragsB <- slot(t+1), compute tile t on fragsA
    RD_FRAGS(afB, bfB, s1);
    MFMA_ALL(afA, bfA);
    WAIT_BARRIER(4);
    STAGE(s0, koff); koff += 32;   // tile tp+4 into just-freed slot
    // t = tp+1: prefetch fragsA <- slot(t+1), compute on fragsB
    RD_FRAGS(afA, bfA, s2);
    MFMA_ALL(afB, bfB);
    WAIT_BARRIER(4);
    STAGE(s1, koff); koff += 32;   // tile tp+5
  }

  // ---- tail: tiles 126..129 (no more staging after tile 129) ---------------
  // t=126: fragsA holds tile 126
  RD_FRAGS(afB, bfB, (127 & 3) * BUFS);
  MFMA_ALL(afA, bfA);
  WAIT_BARRIER(4);                 // slot(128) resident block-wide
  // t=127
  RD_FRAGS(afA, bfA, (128 & 3) * BUFS);
  MFMA_ALL(afB, bfB);
  WAIT_BARRIER(0);                 // slot(129) resident block-wide
  // t=128
  RD_FRAGS(afB, bfB, (129 & 3) * BUFS);
  MFMA_ALL(afA, bfA);
  // t=129 (compiler inserts lgkmcnt for the final frag reads)
  MFMA_ALL(afB, bfB);

#undef STAGE
#undef RD_FRAGS
#undef MFMA_ALL
#undef WAIT_BARRIER

  // ---- epilogue: C/D layout col=lane&15, row=(lane>>4)*4+reg ---------------
#pragma unroll
  for (int j = 0; j < 4; ++j) {
    const int col = colBase + wn + j * 16 + fr;
    const float bv = bias[col];
#pragma unroll
    for (int i = 0; i < 8; ++i) {
      const int r0 = rowBase + wm + i * 16 + q * 4;
#pragma unroll
      for (int r = 0; r < 4; ++r)
        out[(size_t)(r0 + r) * N_DIM + col] = acc[i][j][r] + bv;
    }
  }
}

extern "C" void kernel_launch(void* const* d_in, const int* in_sizes, int n_in,
                              void* d_out, int out_size, void* d_ws, size_t ws_size,
                              hipStream_t stream) {
  const float* x    = (const float*)d_in[0];  // (4,2048,4096)
  const float* A    = (const float*)d_in[1];  // (64,4096)
  const float* B    = (const float*)d_in[2];  // (4096,64)
  const float* W    = (const float*)d_in[3];  // (4096,4096)
  const float* bias = (const float*)d_in[4];  // (4096,)
  float* out = (float*)d_out;

  // workspace layout (all 16B-aligned):
  //   xext  [8192][4160] bf16  = 68.16 MB
  //   wext  [4096][4160] bf16  = 34.08 MB
  //   abf   [64][4096]   bf16  =  0.52 MB
  //   zpart [8][8192][64] fp32 = 16.78 MB
  unsigned short* xext = (unsigned short*)d_ws;
  unsigned short* wext = xext + (size_t)M_DIM * KX;
  unsigned short* abf  = wext + (size_t)N_DIM * KX;
  float*          zpart = (float*)(abf + (size_t)R_DIM * DK);

  // W/B/A fp32->bf16 (x is converted inside zgemm)
  cvt_wba_kernel<<<8448, 256, 0, stream>>>(W, B, A, wext, abf);

  // fused x-cvt + z partials via MFMA split-K GEMM
  dim3 zgrid(M_DIM / 128, SPLITK);  // 64 x 8
  zgemm_kernel<<<zgrid, 256, 0, stream>>>(x, abf, xext, zpart);
  // reduce + soft-topk mask -> x_ext[:, 4096:]
  mask_kernel<<<M_DIM / 4, 256, 0, stream>>>(zpart, xext);

  // main GEMM: 512 blocks (32 bm x 16 bn), 512 threads, 128 KB dynamic LDS
  gemm_kernel<<<dim3(32 * 16), 512, RING * BUFS * sizeof(unsigned short), stream>>>(
      xext, wext, bias, out);
}

// Round 7
// 526.971 us; speedup vs baseline: 1.2436x; 1.0234x over previous
//
#include <hip/hip_runtime.h>
#include <hip/hip_bf16.h>

// Problem constants (fixed shapes from setup_inputs)
#define M_DIM 8192   // B*S = 4*2048
#define N_DIM 4096   // D_OUT
#define DK    4096   // D_IN
#define R_DIM 64
#define KX    4160   // DK + R_DIM (K-extended GEMM)
#define SPLITK 8
#define KCHUNK (DK / SPLITK)  // 512
// SCALE = ALPHA/K = 16/16 = 1.0

// main gemm tiling: 256x256 tile, BK=32, 4-deep LDS ring, 8 waves (2Mx4N)
#define BM 256
#define BN 256
#define BK 32
#define NT (KX / BK)            // 130 K-tiles
#define ATILE (BM * BK)         // 8192 shorts = 16 KB per operand per buffer
#define BUFS (2 * ATILE)        // 16384 shorts per ring slot (A + B)
#define RING 4                  // 4 * 32 KB = 128 KB LDS

typedef __bf16 bf16x8 __attribute__((ext_vector_type(8)));
typedef float f32x4 __attribute__((ext_vector_type(4)));
typedef unsigned short ushort8 __attribute__((ext_vector_type(8)));

__device__ __forceinline__ unsigned short f2bf_rne(float f) {
  union { float f; unsigned int u; } v; v.f = f;
  unsigned int u = v.u;
  return (unsigned short)((u + 0x7fffu + ((u >> 16) & 1u)) >> 16);
}

// async global->LDS, 16B per lane; lds dest is wave-uniform base + lane*16
__device__ __forceinline__ void load16_to_lds(const void* g, void* l) {
  __builtin_amdgcn_global_load_lds(
      (__attribute__((address_space(1))) void*)(unsigned long long)(const char*)g,
      (__attribute__((address_space(3))) void*)(unsigned int)(unsigned long long)(char*)l,
      16, 0, 0);
}

// ---------------- fp32 -> bf16 conversion, all four tensors in ONE launch ----------------
// (Round-3 proven form: fully-coalesced 1KB/wave writes keep xext L3-hot for gemm;
// round-5's scattered zgemm writes cost gemm +135MB FETCH / +13.5us.)
__global__ __launch_bounds__(256) void cvt_all_kernel(
    const float* __restrict__ x, const float* __restrict__ W,
    const float* __restrict__ B, const float* __restrict__ A,
    unsigned short* __restrict__ xext, unsigned short* __restrict__ wext,
    unsigned short* __restrict__ abf) {
  const int b = blockIdx.x;
  const float* src; unsigned short* dst;
  int shift, mask, rowstride, coloff; long long base;
  if (b < 16384)      { src = x; dst = xext; shift = 12; mask = 4095; rowstride = KX; coloff = 0;  base = (long long)b * 2048; }
  else if (b < 24576) { src = W; dst = wext; shift = 12; mask = 4095; rowstride = KX; coloff = 0;  base = (long long)(b - 16384) * 2048; }
  else if (b < 24704) { src = B; dst = wext; shift = 6;  mask = 63;   rowstride = KX; coloff = DK; base = (long long)(b - 24576) * 2048; }
  else                { src = A; dst = abf;  shift = 12; mask = 4095; rowstride = DK; coloff = 0;  base = (long long)(b - 24704) * 2048; }
  long long idx = base + (long long)threadIdx.x * 8;
  long long row = idx >> shift;
  int col = (int)(idx & mask);
  float4 f0 = *(const float4*)(src + idx);
  float4 f1 = *(const float4*)(src + idx + 4);
  ushort8 o;
  o[0] = f2bf_rne(f0.x); o[1] = f2bf_rne(f0.y);
  o[2] = f2bf_rne(f0.z); o[3] = f2bf_rne(f0.w);
  o[4] = f2bf_rne(f1.x); o[5] = f2bf_rne(f1.y);
  o[6] = f2bf_rne(f1.z); o[7] = f2bf_rne(f1.w);
  *(ushort8*)(dst + row * (long long)rowstride + coloff + col) = o;
}

// ---------------- z partials: zpart[kc] = xext[:, kc*512:(kc+1)*512] @ Abf^T ----------------
__global__ __launch_bounds__(256) void zgemm_kernel(
    const unsigned short* __restrict__ Xg,   // [M_DIM][KX] bf16
    const unsigned short* __restrict__ Ab,   // [R_DIM][DK] bf16
    float* __restrict__ zpart) {             // [SPLITK][M_DIM][64] fp32
  __shared__ unsigned short As[128][32];  // 8 KB (x rows)
  __shared__ unsigned short Bs[64][32];   // 4 KB (A rows)

  const int tid = threadIdx.x;
  const int wave = tid >> 6;
  const int lane = tid & 63;
  const int rowBase = blockIdx.x * 128;
  const int kc = blockIdx.y;
  const int kBase = kc * KCHUNK;
  const int wm = wave * 32;

  const int c0 = wave, c1 = wave + 4;
  const int srow = lane >> 2;
  const int sseg = (lane & 3) * 8;

  const unsigned short* aP0 = Xg + (size_t)(rowBase + c0 * 16 + srow) * KX + kBase + sseg;
  const unsigned short* aP1 = Xg + (size_t)(rowBase + c1 * 16 + srow) * KX + kBase + sseg;
  const unsigned short* bP0 = Ab + (size_t)(wave * 16 + srow) * DK + kBase + sseg;
  unsigned short* aL0 = &As[c0 * 16][0];
  unsigned short* aL1 = &As[c1 * 16][0];
  unsigned short* bL0 = &Bs[wave * 16][0];

  f32x4 acc[2][4] = {};
  const int fr = lane & 15;
  const int fk = (lane >> 4) * 8;

  for (int k0 = 0; k0 < KCHUNK; k0 += 32) {
    __syncthreads();
    load16_to_lds(aP0 + k0, aL0);
    load16_to_lds(aP1 + k0, aL1);
    load16_to_lds(bP0 + k0, bL0);
    __syncthreads();

    bf16x8 afrag[2], bfrag[4];
#pragma unroll
    for (int i = 0; i < 2; ++i)
      afrag[i] = *(const bf16x8*)&As[wm + i * 16 + fr][fk];
#pragma unroll
    for (int j = 0; j < 4; ++j)
      bfrag[j] = *(const bf16x8*)&Bs[j * 16 + fr][fk];
#pragma unroll
    for (int i = 0; i < 2; ++i)
#pragma unroll
      for (int j = 0; j < 4; ++j)
        acc[i][j] = __builtin_amdgcn_mfma_f32_16x16x32_bf16(afrag[i], bfrag[j],
                                                            acc[i][j], 0, 0, 0);
  }

  const int quad = lane >> 4;
#pragma unroll
  for (int j = 0; j < 4; ++j) {
    int col = j * 16 + fr;
#pragma unroll
    for (int i = 0; i < 2; ++i) {
      int row0 = rowBase + wm + i * 16 + quad * 4;
#pragma unroll
      for (int r = 0; r < 4; ++r)
        zpart[((size_t)kc * M_DIM + row0 + r) * R_DIM + col] = acc[i][j][r];
    }
  }
}

// ---------------- reduce partials, soft top-k mask, write bf16 into x_ext tail ----------------
__global__ __launch_bounds__(256) void mask_kernel(
    const float* __restrict__ zpart, unsigned short* __restrict__ xext) {
  const int wave = threadIdx.x >> 6;
  const int lane = threadIdx.x & 63;
  const int row = blockIdx.x * 4 + wave;

  float v = 0.f;
#pragma unroll
  for (int k = 0; k < SPLITK; ++k)
    v += zpart[((size_t)k * M_DIM + row) * R_DIM + lane];

  float a = fabsf(v);
  // rank-select the 16th-largest |z| (tie-safe): cnt_gt <= 15 < cnt_ge
  int cnt_gt = 0, cnt_ge = 0;
#pragma unroll
  for (int i = 0; i < 64; ++i) {
    float o = __shfl(a, i);
    cnt_gt += (o > a) ? 1 : 0;
    cnt_ge += (o >= a) ? 1 : 0;
  }
  float cand = (cnt_gt <= 15 && cnt_ge > 15) ? a : -1.f;
#pragma unroll
  for (int off = 32; off; off >>= 1) cand = fmaxf(cand, __shfl_xor(cand, off));
  float thr = cand;
  float mask = 1.f / (1.f + __expf(-(a - thr) * 10.0f));  // TEMP=0.1
  xext[(size_t)row * KX + DK + lane] = f2bf_rne(v * mask);  // SCALE == 1.0
}

// ---------------- main GEMM: out[m][n] = sum_k xext[m][k]*wext[n][k] + bias[n] ----------------
// Round-3 sync structure (4-deep ring, reg-double-buffered frags, one barrier
// per tile, counted vmcnt(4)+lgkmcnt(12)) with ONE change: the 12 next-tile
// ds_reads are source-interleaved into the 32-MFMA cluster as 4 groups of
// {3 reads, 8 MFMAs}, pinned by sched_barrier(0) -- overlaps the LDS port
// (~1150 cyc/tile) with the matrix pipe (~1242 cyc/tile) instead of serial.
__global__ __launch_bounds__(512, 2) void gemm_kernel(
    const unsigned short* __restrict__ Ag,   // [M_DIM][KX] bf16
    const unsigned short* __restrict__ Bg,   // [N_DIM][KX] bf16
    const float* __restrict__ bias,
    float* __restrict__ out) {
  extern __shared__ unsigned short sm[];  // RING * BUFS shorts = 128 KB

  const int tid = threadIdx.x;
  const int w = tid >> 6;
  const int lane = tid & 63;

  // T1: 512 blocks = 8 XCDs x 64; each XCD gets 4 consecutive bm rows
  const int bid = blockIdx.x;
  const int swz = (bid & 7) * 64 + (bid >> 3);
  const int bm = swz >> 4;   // 0..31
  const int bn = swz & 15;   // 0..15
  const int rowBase = bm * BM;
  const int colBase = bn * BN;

  // wave tile: 2 (M) x 4 (N); per-wave output 128x64
  const int wm = (w >> 2) * 128;
  const int wn = (w & 3) * 64;

  // ---- staging setup -------------------------------------------------------
  const int srow = lane >> 2;                                // 0..15
  const int sseg = (((lane & 3) ^ ((lane >> 3) & 3)) * 8);   // swizzled 8-short seg
  const int c0 = w * 2, c1 = w * 2 + 1;                      // 16-row chunks
  const unsigned short* aS0 = Ag + (size_t)(rowBase + c0 * 16 + srow) * KX + sseg;
  const unsigned short* aS1 = Ag + (size_t)(rowBase + c1 * 16 + srow) * KX + sseg;
  const unsigned short* bS0 = Bg + (size_t)(colBase + c0 * 16 + srow) * KX + sseg;
  const unsigned short* bS1 = Bg + (size_t)(colBase + c1 * 16 + srow) * KX + sseg;
  const int aD0 = c0 * 512, aD1 = c1 * 512;                  // shorts, wave-uniform
  const int bD0 = ATILE + c0 * 512, bD1 = ATILE + c1 * 512;

#define STAGE(bufS, koff)                                \
  do {                                                   \
    load16_to_lds(aS0 + (koff), &sm[(bufS) + aD0]);      \
    load16_to_lds(aS1 + (koff), &sm[(bufS) + aD1]);      \
    load16_to_lds(bS0 + (koff), &sm[(bufS) + bD0]);      \
    load16_to_lds(bS1 + (koff), &sm[(bufS) + bD1]);      \
  } while (0)

  f32x4 acc[8][4] = {};
  const int fr = lane & 15;
  const int q = lane >> 4;
  const int rdc = ((q ^ ((fr >> 1) & 3)) * 8);  // T2 read-side XOR (2-way = free)

#define LD_A(S, i_) (*(const bf16x8*)&sm[(S) + (wm + (i_) * 16 + fr) * 32 + rdc])
#define LD_B(S, j_) (*(const bf16x8*)&sm[(S) + ATILE + (wn + (j_) * 16 + fr) * 32 + rdc])

#define MFMA_ROW(AF, BF, i_)                                                  \
  do {                                                                        \
    acc[i_][0] = __builtin_amdgcn_mfma_f32_16x16x32_bf16(AF[i_], BF[0], acc[i_][0], 0, 0, 0); \
    acc[i_][1] = __builtin_amdgcn_mfma_f32_16x16x32_bf16(AF[i_], BF[1], acc[i_][1], 0, 0, 0); \
    acc[i_][2] = __builtin_amdgcn_mfma_f32_16x16x32_bf16(AF[i_], BF[2], acc[i_][2], 0, 0, 0); \
    acc[i_][3] = __builtin_amdgcn_mfma_f32_16x16x32_bf16(AF[i_], BF[3], acc[i_][3], 0, 0, 0); \
  } while (0)

  // Interleaved tile step: 4 groups of {3 next-tile ds_reads, 8 current MFMAs},
  // group boundaries pinned so the LDS burst spreads across the MFMA cluster.
#define STEP(AFc, BFc, AFn, BFn, S)                                           \
  do {                                                                        \
    __builtin_amdgcn_s_setprio(1);                                            \
    AFn[0] = LD_A(S, 0); AFn[1] = LD_A(S, 1); AFn[2] = LD_A(S, 2);            \
    MFMA_ROW(AFc, BFc, 0); MFMA_ROW(AFc, BFc, 1);                             \
    __builtin_amdgcn_sched_barrier(0);                                        \
    AFn[3] = LD_A(S, 3); AFn[4] = LD_A(S, 4); AFn[5] = LD_A(S, 5);            \
    MFMA_ROW(AFc, BFc, 2); MFMA_ROW(AFc, BFc, 3);                             \
    __builtin_amdgcn_sched_barrier(0);                                        \
    AFn[6] = LD_A(S, 6); AFn[7] = LD_A(S, 7); BFn[0] = LD_B(S, 0);            \
    MFMA_ROW(AFc, BFc, 4); MFMA_ROW(AFc, BFc, 5);                             \
    __builtin_amdgcn_sched_barrier(0);                                        \
    BFn[1] = LD_B(S, 1); BFn[2] = LD_B(S, 2); BFn[3] = LD_B(S, 3);            \
    MFMA_ROW(AFc, BFc, 6); MFMA_ROW(AFc, BFc, 7);                             \
    __builtin_amdgcn_s_setprio(0);                                            \
  } while (0)

#define RD_FRAGS(AF, BF, S)                                                   \
  do {                                                                        \
    _Pragma("unroll")                                                         \
    for (int i_ = 0; i_ < 8; ++i_) AF[i_] = LD_A(S, i_);                      \
    _Pragma("unroll")                                                         \
    for (int j_ = 0; j_ < 4; ++j_) BF[j_] = LD_B(S, j_);                      \
  } while (0)

#define MFMA_ALL(AF, BF)                                                      \
  do {                                                                        \
    __builtin_amdgcn_s_setprio(1);                                            \
    _Pragma("unroll")                                                         \
    for (int i_ = 0; i_ < 8; ++i_) MFMA_ROW(AF, BF, i_);                      \
    __builtin_amdgcn_s_setprio(0);                                            \
  } while (0)

#define WAIT_BARRIER(VM)                                                      \
  do {                                                                        \
    asm volatile("s_waitcnt vmcnt(" #VM ") lgkmcnt(12)" ::: "memory");        \
    __builtin_amdgcn_sched_barrier(0);                                        \
    __builtin_amdgcn_s_barrier();                                             \
    __builtin_amdgcn_sched_barrier(0);                                        \
  } while (0)

  // ---- prologue: fill the 4-deep ring (tiles 0..3), 16 loads in flight ----
  STAGE(0 * BUFS, 0);
  STAGE(1 * BUFS, 32);
  STAGE(2 * BUFS, 64);
  STAGE(3 * BUFS, 96);
  // slots 0 AND 1 must be resident block-wide before iter 0 (it reads slot 1)
  asm volatile("s_waitcnt vmcnt(8)" ::: "memory");
  __builtin_amdgcn_sched_barrier(0);
  __builtin_amdgcn_s_barrier();
  __builtin_amdgcn_sched_barrier(0);

  bf16x8 afA[8], bfA[4], afB[8], bfB[4];
  RD_FRAGS(afA, bfA, 0);  // fragments of tile 0

  // ---- main loop: pairs t=(tp, tp+1), tp = 0..124; stages tiles 4..129 -----
  int koff = 128;
  for (int tp = 0; tp < 126; tp += 2) {
    const int s0 = (tp & 3) * BUFS;
    const int s1 = ((tp + 1) & 3) * BUFS;
    const int s2 = ((tp + 2) & 3) * BUFS;
    // t = tp: interleaved {reads of slot(t+1), MFMAs of tile t}
    STEP(afA, bfA, afB, bfB, s1);
    WAIT_BARRIER(4);
    STAGE(s0, koff); koff += 32;   // tile tp+4 into just-freed slot
    // t = tp+1
    STEP(afB, bfB, afA, bfA, s2);
    WAIT_BARRIER(4);
    STAGE(s1, koff); koff += 32;   // tile tp+5
  }

  // ---- tail: tiles 126..129 (no more staging after tile 129) ---------------
  RD_FRAGS(afB, bfB, (127 & 3) * BUFS);
  MFMA_ALL(afA, bfA);
  WAIT_BARRIER(4);                 // slot(128) resident block-wide
  RD_FRAGS(afA, bfA, (128 & 3) * BUFS);
  MFMA_ALL(afB, bfB);
  WAIT_BARRIER(0);                 // slot(129) resident block-wide
  RD_FRAGS(afB, bfB, (129 & 3) * BUFS);
  MFMA_ALL(afA, bfA);
  MFMA_ALL(afB, bfB);              // compiler inserts final lgkmcnt

#undef STAGE
#undef LD_A
#undef LD_B
#undef MFMA_ROW
#undef STEP
#undef RD_FRAGS
#undef MFMA_ALL
#undef WAIT_BARRIER

  // ---- epilogue: C/D layout col=lane&15, row=(lane>>4)*4+reg ---------------
#pragma unroll
  for (int j = 0; j < 4; ++j) {
    const int col = colBase + wn + j * 16 + fr;
    const float bv = bias[col];
#pragma unroll
    for (int i = 0; i < 8; ++i) {
      const int r0 = rowBase + wm + i * 16 + q * 4;
#pragma unroll
      for (int r = 0; r < 4; ++r)
        out[(size_t)(r0 + r) * N_DIM + col] = acc[i][j][r] + bv;
    }
  }
}

extern "C" void kernel_launch(void* const* d_in, const int* in_sizes, int n_in,
                              void* d_out, int out_size, void* d_ws, size_t ws_size,
                              hipStream_t stream) {
  const float* x    = (const float*)d_in[0];  // (4,2048,4096)
  const float* A    = (const float*)d_in[1];  // (64,4096)
  const float* B    = (const float*)d_in[2];  // (4096,64)
  const float* W    = (const float*)d_in[3];  // (4096,4096)
  const float* bias = (const float*)d_in[4];  // (4096,)
  float* out = (float*)d_out;

  // workspace layout (all 16B-aligned):
  //   xext  [8192][4160] bf16  = 68.16 MB
  //   wext  [4096][4160] bf16  = 34.08 MB
  //   abf   [64][4096]   bf16  =  0.52 MB
  //   zpart [8][8192][64] fp32 = 16.78 MB
  unsigned short* xext = (unsigned short*)d_ws;
  unsigned short* wext = xext + (size_t)M_DIM * KX;
  unsigned short* abf  = wext + (size_t)N_DIM * KX;
  float*          zpart = (float*)(abf + (size_t)R_DIM * DK);

  // all four fp32->bf16 conversions in one launch
  cvt_all_kernel<<<24832, 256, 0, stream>>>(x, W, B, A, xext, wext, abf);

  // z partials via MFMA split-K GEMM
  dim3 zgrid(M_DIM / 128, SPLITK);  // 64 x 8
  zgemm_kernel<<<zgrid, 256, 0, stream>>>(xext, abf, zpart);
  // reduce + soft-topk mask -> x_ext[:, 4096:]
  mask_kernel<<<M_DIM / 4, 256, 0, stream>>>(zpart, xext);

  // main GEMM: 512 blocks (32 bm x 16 bn), 512 threads, 128 KB dynamic LDS
  gemm_kernel<<<dim3(32 * 16), 512, RING * BUFS * sizeof(unsigned short), stream>>>(
      xext, wext, bias, out);
}